// Round 2
// baseline (1043.305 us; speedup 1.0000x reference)
//
#include <hip/hip_runtime.h>

typedef unsigned short u16;
typedef short s16x8 __attribute__((ext_vector_type(8)));
typedef __bf16 bf16x8 __attribute__((ext_vector_type(8)));
typedef float f32x4 __attribute__((ext_vector_type(4)));

// ---------- helpers ----------

__device__ __forceinline__ u16 f2bf(float f) {
  union { float f; unsigned u; } x; x.f = f;
  unsigned r = (x.u + 0x7fffu + ((x.u >> 16) & 1u)) >> 16;  // RNE
  return (u16)r;
}

__device__ __forceinline__ float bf2f(u16 b) {
  union { unsigned u; float f; } x; x.u = ((unsigned)b) << 16;
  return x.f;
}

__device__ __forceinline__ f32x4 mfma_bf16_16x16x32(s16x8 a, s16x8 b, f32x4 c) {
  return __builtin_amdgcn_mfma_f32_16x16x32_bf16(
      __builtin_bit_cast(bf16x8, a), __builtin_bit_cast(bf16x8, b), c, 0, 0, 0);
}

__device__ __forceinline__ void gl_lds16(const u16* g, u16* l) {
  __builtin_amdgcn_global_load_lds(
      (__attribute__((address_space(1))) unsigned int*)g,
      (__attribute__((address_space(3))) unsigned int*)l, 16, 0, 0);
}

// ---------- prep kernels ----------

__global__ __launch_bounds__(256) void cvt_bf16(const float* __restrict__ src,
                                                u16* __restrict__ dst, int n) {
  int i = (blockIdx.x * 256 + threadIdx.x) * 4;
  if (i + 3 < n) {
    float4 f = *(const float4*)(src + i);
    ushort4 o;
    o.x = f2bf(f.x); o.y = f2bf(f.y); o.z = f2bf(f.z); o.w = f2bf(f.w);
    *(ushort4*)(dst + i) = o;
  }
}

// bm[w][h][i][j] = bias_table[rel_index[ij]*16+h] + mask[w][ij]  (bf16)
__global__ __launch_bounds__(256) void build_bm(const float* __restrict__ tbl,
                                                const int* __restrict__ ridx,
                                                const float* __restrict__ mask,
                                                u16* __restrict__ bm) {
  int t = blockIdx.x * 256 + threadIdx.x;  // over 64*16*2401
  if (t < 64 * 16 * 2401) {
    int j = t % 2401;
    int wh = t / 2401;
    int h = wh & 15, wd = wh >> 4;
    bm[t] = f2bf(tbl[ridx[j] * 16 + h] + mask[wd * 2401 + j]);
  }
}

// ---------- GEMM: C[M][N] = A[M][K] * B[N][K]^T + bias[N] ----------
// 128x128 tile, BK=64, 256 threads (4 waves 2x2), 16x16x32 MFMA.
// LDS chunk swizzle: slot c holds global k-chunk (c ^ (row&7)) -> conflict-free
// ds_read_b128 (2-way, free) while keeping global_load_lds's lane*16B layout.

template <bool OUT_BF16>
__global__ __launch_bounds__(256) void gemm_bt(const u16* __restrict__ A,
                                               const u16* __restrict__ B,
                                               const float* __restrict__ bias,
                                               void* __restrict__ C,
                                               int M, int N, int K) {
  __shared__ u16 As[128 * 64];
  __shared__ u16 Bs[128 * 64];
  const int t = threadIdx.x;
  const int w = t >> 6, l = t & 63;
  const int quad = l >> 4, lo = l & 15;
  const long m0 = (long)blockIdx.y * 128;
  const long n0 = (long)blockIdx.x * 128;
  const int wm = (w >> 1) * 64, wn = (w & 1) * 64;

  f32x4 acc[4][4] = {};

  // staging: linear chunk q = i*256 + t; row = q>>3, slot c = q&7,
  // global k-chunk kc = c ^ (row&7)
  const u16* gA[4]; const u16* gB[4]; u16* lA[4]; u16* lB[4];
#pragma unroll
  for (int i = 0; i < 4; ++i) {
    int q = i * 256 + t;
    int row = q >> 3, c = q & 7;
    int kc = c ^ (row & 7);
    gA[i] = A + (m0 + row) * (long)K + kc * 8;
    gB[i] = B + (n0 + row) * (long)K + kc * 8;
    lA[i] = As + q * 8;
    lB[i] = Bs + q * 8;
  }

  for (int k0 = 0; k0 < K; k0 += 64) {
#pragma unroll
    for (int i = 0; i < 4; ++i) gl_lds16(gA[i] + k0, lA[i]);
#pragma unroll
    for (int i = 0; i < 4; ++i) gl_lds16(gB[i] + k0, lB[i]);
    __syncthreads();

#pragma unroll
    for (int kk = 0; kk < 2; ++kk) {
      s16x8 af[4], bfv[4];
#pragma unroll
      for (int i = 0; i < 4; ++i) {
        int ra = wm + i * 16 + lo;
        int rb = wn + i * 16 + lo;
        int ca = (kk * 4 + quad) ^ (ra & 7);
        int cb = (kk * 4 + quad) ^ (rb & 7);
        af[i]  = *(const s16x8*)(As + (ra * 8 + ca) * 8);
        bfv[i] = *(const s16x8*)(Bs + (rb * 8 + cb) * 8);
      }
#pragma unroll
      for (int mt = 0; mt < 4; ++mt)
#pragma unroll
        for (int nt = 0; nt < 4; ++nt)
          acc[mt][nt] = mfma_bf16_16x16x32(af[mt], bfv[nt], acc[mt][nt]);
    }
    __syncthreads();
  }

  // epilogue: D[row = quad*4+r][col = lane&15]
#pragma unroll
  for (int mt = 0; mt < 4; ++mt) {
#pragma unroll
    for (int nt = 0; nt < 4; ++nt) {
      long col = n0 + wn + nt * 16 + lo;
      float bv = bias[col];
      long rowb = m0 + wm + mt * 16 + quad * 4;
#pragma unroll
      for (int r = 0; r < 4; ++r) {
        float v = acc[mt][nt][r] + bv;
        long off = (rowb + r) * (long)N + col;
        if (OUT_BF16) ((u16*)C)[off] = f2bf(v);
        else          ((float*)C)[off] = v;
      }
    }
  }
}

// ---------- fused window attention ----------
// one wave per (window b, head h); 64-thread blocks.
// qkv row layout: col = s*512 + h*32 + d, row stride 1536.

#define PS 72  // LDS row stride (u16): 144 B = 16B-aligned, ~2-way banks

__global__ __launch_bounds__(64) void attn_kernel(const u16* __restrict__ qkv,
                                                  const u16* __restrict__ bm,
                                                  u16* __restrict__ ao) {
  __shared__ u16 P[64 * PS];   // P tile (A-operand staging)
  __shared__ u16 VT[32 * PS];  // V^T: VT[d][j]
  const int l = threadIdx.x;
  const int quad = l >> 4, lo = l & 15;
  const int u = blockIdx.x;
  const int b = u >> 4, h = u & 15;

  const u16* qp = qkv + (long)b * 49 * 1536 + h * 32;
  const u16* kp = qp + 512;
  const u16* vp = qp + 1024;

  // zero VT (columns j>=49 must be 0 for the PV K-padding)
#pragma unroll
  for (int z = 0; z < 18; ++z) ((unsigned*)VT)[z * 64 + l] = 0;

  // stage V transposed: coalesced dword loads (full 64B rows per 16 lanes)
#pragma unroll
  for (int rep = 0; rep < 13; ++rep) {
    int j = rep * 4 + quad;
    if (j < 49) {
      unsigned vd = *(const unsigned*)(vp + (long)j * 1536 + lo * 2);
      VT[(2 * lo) * PS + j] = (u16)vd;
      VT[(2 * lo + 1) * PS + j] = (u16)(vd >> 16);
    }
  }

  const s16x8 zero8 = {};
  s16x8 qf[4], kf[4];
#pragma unroll
  for (int mt = 0; mt < 4; ++mt) {
    int m = mt * 16 + lo;
    qf[mt] = (m < 49) ? *(const s16x8*)(qp + (long)m * 1536 + quad * 8) : zero8;
    kf[mt] = (m < 49) ? *(const s16x8*)(kp + (long)m * 1536 + quad * 8) : zero8;
  }

  f32x4 S[4][4] = {};
#pragma unroll
  for (int mt = 0; mt < 4; ++mt)
#pragma unroll
    for (int nt = 0; nt < 4; ++nt)
      S[mt][nt] = mfma_bf16_16x16x32(qf[mt], kf[nt], S[mt][nt]);

  const float scale = 0.17677669529663687f;  // 32^-0.5
  const u16* bmp = bm + ((long)(b & 63) * 16 + h) * 2401;

  // logits + row softmax (row lives in a 16-lane group)
#pragma unroll
  for (int mt = 0; mt < 4; ++mt) {
#pragma unroll
    for (int r = 0; r < 4; ++r) {
      int row = mt * 16 + quad * 4 + r;
      int rr = row < 49 ? row : 48;  // dead rows: keep reads in-bounds
      float vals[4];
#pragma unroll
      for (int nt = 0; nt < 4; ++nt) {
        int col = nt * 16 + lo;
        vals[nt] = (col < 49)
                       ? S[mt][nt][r] * scale + bf2f(bmp[rr * 49 + col])
                       : -1e30f;
      }
      float rm = fmaxf(fmaxf(vals[0], vals[1]), fmaxf(vals[2], vals[3]));
#pragma unroll
      for (int off = 1; off < 16; off <<= 1) rm = fmaxf(rm, __shfl_xor(rm, off, 16));
      float s = 0.f;
#pragma unroll
      for (int nt = 0; nt < 4; ++nt) {
        vals[nt] = __expf(vals[nt] - rm);
        s += vals[nt];
      }
#pragma unroll
      for (int off = 1; off < 16; off <<= 1) s += __shfl_xor(s, off, 16);
      float is = 1.f / s;
#pragma unroll
      for (int nt = 0; nt < 4; ++nt) S[mt][nt][r] = vals[nt] * is;
    }
  }

  // P (C-layout) -> LDS (stride PS), then reload as A-operand frags
#pragma unroll
  for (int mt = 0; mt < 4; ++mt)
#pragma unroll
    for (int nt = 0; nt < 4; ++nt)
#pragma unroll
      for (int r = 0; r < 4; ++r)
        P[(mt * 16 + quad * 4 + r) * PS + nt * 16 + lo] = f2bf(S[mt][nt][r]);

  // O = P * V : M=64, N=32 (2 tiles), K=64 (2 tiles of 32)
  f32x4 O[4][2] = {};
#pragma unroll
  for (int kt = 0; kt < 2; ++kt) {
    s16x8 vb0 = *(const s16x8*)(VT + lo * PS + kt * 32 + quad * 8);
    s16x8 vb1 = *(const s16x8*)(VT + (16 + lo) * PS + kt * 32 + quad * 8);
#pragma unroll
    for (int mt = 0; mt < 4; ++mt) {
      s16x8 pa = *(const s16x8*)(P + (mt * 16 + lo) * PS + kt * 32 + quad * 8);
      O[mt][0] = mfma_bf16_16x16x32(pa, vb0, O[mt][0]);
      O[mt][1] = mfma_bf16_16x16x32(pa, vb1, O[mt][1]);
    }
  }

  // store attn_out[b*49+row][h*32 + d], bf16
  u16* op = ao + (long)b * 49 * 512 + h * 32;
#pragma unroll
  for (int mt = 0; mt < 4; ++mt)
#pragma unroll
    for (int nt = 0; nt < 2; ++nt)
#pragma unroll
      for (int r = 0; r < 4; ++r) {
        int row = mt * 16 + quad * 4 + r;
        if (row < 49) op[(long)row * 512 + nt * 16 + lo] = f2bf(O[mt][nt][r]);
      }
}

// ---------- launch ----------

extern "C" void kernel_launch(void* const* d_in, const int* in_sizes, int n_in,
                              void* d_out, int out_size, void* d_ws, size_t ws_size,
                              hipStream_t stream) {
  const float* x      = (const float*)d_in[0];
  const float* mask   = (const float*)d_in[1];
  const float* qkv_w  = (const float*)d_in[2];
  const float* qkv_b  = (const float*)d_in[3];
  const float* proj_w = (const float*)d_in[4];
  const float* proj_b = (const float*)d_in[5];
  const float* tbl    = (const float*)d_in[6];
  const int*   ridx   = (const int*)d_in[7];

  // ws layout (u16 elements):
  // xb: 100352*512 (reused as attn_out after GEMM1) | qkvb: 100352*1536
  // wq: 1536*512 | wp: 512*512 | bm: 64*16*2401 (bf16)
  u16* xb   = (u16*)d_ws;
  u16* qkvb = xb + 51380224;
  u16* wq   = qkvb + 154140672;
  u16* wp   = wq + 786432;
  u16* bm   = wp + 262144;

  cvt_bf16<<<50176, 256, 0, stream>>>(x, xb, 51380224);
  cvt_bf16<<<768, 256, 0, stream>>>(qkv_w, wq, 786432);
  cvt_bf16<<<256, 256, 0, stream>>>(proj_w, wp, 262144);
  build_bm<<<9604, 256, 0, stream>>>(tbl, ridx, mask, bm);

  // qkv = x @ qkv_w^T + qkv_b   (bf16 out)
  gemm_bt<true><<<dim3(12, 784), 256, 0, stream>>>(xb, wq, qkv_b, qkvb,
                                                   100352, 1536, 512);
  // attention -> attn_out (reuse xb region)
  attn_kernel<<<32768, 64, 0, stream>>>(qkvb, bm, xb);

  // out = attn_out @ proj_w^T + proj_b   (fp32 out)
  gemm_bt<false><<<dim3(4, 784), 256, 0, stream>>>(xb, wp, proj_b, d_out,
                                                   100352, 512, 512);
}